// Round 2
// baseline (32.785 us; speedup 1.0000x reference)
//
#include <hip/hip_runtime.h>

#define BB 16
#define NN 65536
#define KK 64
#define TPB 256
#define NCHUNK 4
#define CHUNK 256                       // elements per chunk = TPB (1 elem/thread/chunk)
#define CHUNK_STRIDE (NN / NCHUNK)      // 16384: chunks spread across the row for load balance

__global__ __launch_bounds__(TPB) void frac_deriv_kernel(
    const float* __restrict__ x,
    const float* __restrict__ loc,
    const float* __restrict__ scale,
    const float* __restrict__ eps,
    const int* __restrict__ lags,
    float* __restrict__ out)
{
    __shared__ int   j_sh[KK];
    __shared__ float w_sh[KK];

    const int tid = threadIdx.x;
    if (tid < KK) {
        // alpha = clip(loc + softplus(scale)*eps, 0.01, 0.99), in double
        double s  = (double)scale[0];
        double sp = (s > 20.0) ? s : log1p(exp(s));
        double a  = (double)loc[0] + sp * (double)eps[0];
        a = fmin(fmax(a, 0.01), 0.99);
        // c = alpha * exp(-lgamma(1-alpha)) * (n-1)/k ; fold into per-lag weight
        double c = a * exp(-lgamma(1.0 - a)) * ((double)(NN - 1) / (double)KK);
        int j = lags[tid];
        j = (j < 1) ? 1 : ((j > NN - 1) ? NN - 1 : j);
        j_sh[tid] = j;
        w_sh[tid] = (float)(c * exp(-(a + 1.0) * log((double)j)));
    }
    __syncthreads();

    // Bijective XCD swizzle: 1024 blocks, each XCD gets 128 contiguous -> 2 rows, L2-resident.
    const int bid = blockIdx.x;
    const int swz = (bid & 7) * 128 + (bid >> 3);
    const int b   = swz >> 6;        // row  [0,16)
    const int q   = swz & 63;        // position within row [0,64)

    const float* __restrict__ xr = x + (size_t)b * NN;

    int   T[NCHUNK];
    float xt[NCHUNK];
#pragma unroll
    for (int i = 0; i < NCHUNK; ++i) {
        T[i]  = q * CHUNK + i * CHUNK_STRIDE;
        xt[i] = xr[T[i] + tid];
    }

    double acc[NCHUNK];
#pragma unroll
    for (int i = 0; i < NCHUNK; ++i) acc[i] = 0.0;

    for (int mo = 0; mo < KK; mo += 8) {
        float g[NCHUNK];
#pragma unroll
        for (int i = 0; i < NCHUNK; ++i) g[i] = 0.0f;

#pragma unroll
        for (int mi = 0; mi < 8; ++mi) {
            const int m = mo + mi;
            // lag & weight are wave-uniform: hoist to SGPR so the gather uses
            // a scalar base (2 SALU per m) instead of per-lane 64-bit addr math.
            const int   j = __builtin_amdgcn_readfirstlane(j_sh[m]);
            const float w = __uint_as_float(
                (unsigned)__builtin_amdgcn_readfirstlane((int)__float_as_uint(w_sh[m])));
            const float* xmj = xr - j;   // scalar base; only dereferenced where valid

#pragma unroll
            for (int i = 0; i < NCHUNK; ++i) {
                if (j <= T[i] + (CHUNK - 1)) {          // uniform: chunk not fully masked
                    float diff;
                    if (j <= T[i]) {                     // uniform fast path: no mask needed
                        const float xg = xmj[T[i] + tid];
                        diff = xt[i] - xg;
                    } else {                             // rare straddle: per-lane mask + clamp
                        const int d  = T[i] + tid - j;
                        const float xg = xr[(d < 0) ? 0 : d];
                        diff = (d >= 0) ? (xt[i] - xg) : 0.0f;
                    }
                    g[i] = fmaf(diff, w, g[i]);
                }
            }
        }
#pragma unroll
        for (int i = 0; i < NCHUNK; ++i) acc[i] += (double)g[i];
    }

    float* __restrict__ orow = out + (size_t)b * NN;
#pragma unroll
    for (int i = 0; i < NCHUNK; ++i) orow[T[i] + tid] = (float)acc[i];
}

extern "C" void kernel_launch(void* const* d_in, const int* in_sizes, int n_in,
                              void* d_out, int out_size, void* d_ws, size_t ws_size,
                              hipStream_t stream) {
    const float* x     = (const float*)d_in[0];
    const float* loc   = (const float*)d_in[1];
    const float* scale = (const float*)d_in[2];
    const float* eps   = (const float*)d_in[3];
    const int*   lags  = (const int*)d_in[4];
    float* out = (float*)d_out;

    const int nblocks = (BB * NN) / (TPB * NCHUNK); // 1024
    frac_deriv_kernel<<<nblocks, TPB, 0, stream>>>(x, loc, scale, eps, lags, out);
}

// Round 3
// 21.676 us; speedup vs baseline: 1.5125x; 1.5125x over previous
//
#include <hip/hip_runtime.h>

#define BB 16
#define NN 65536
#define KK 64
#define TPB 256
#define NCHUNK 4
#define CHUNK 256
#define CHUNK_STRIDE (NN / NCHUNK)   // 16384: chunks spread across the row

__device__ __forceinline__ float rfl_f(float v) {
    return __uint_as_float((unsigned)__builtin_amdgcn_readfirstlane((int)__float_as_uint(v)));
}

__global__ __launch_bounds__(TPB) void frac_deriv_kernel(
    const float* __restrict__ x,
    const float* __restrict__ loc,
    const float* __restrict__ scale,
    const float* __restrict__ eps,
    const int* __restrict__ lags,
    float* __restrict__ out)
{
    __shared__ int   js_raw[KK];
    __shared__ float ws_raw[KK];
    __shared__ int   js[KK];     // sorted ascending
    __shared__ float ws[KK];     // weights in sorted order
    __shared__ int   cnt[2 * NCHUNK];  // cnt[i]=cf (fully valid), cnt[4+i]=cp (incl. straddle)

    const int tid = threadIdx.x;
    // Bijective XCD swizzle: 1024 blocks -> each XCD gets 128 contiguous = 2 rows.
    const int bid = blockIdx.x;
    const int swz = (bid & 7) * 128 + (bid >> 3);
    const int b   = swz >> 6;    // row [0,16)
    const int q   = swz & 63;    // chunk-group position within row [0,64)

    if (tid < KK) {
        double s  = (double)scale[0];
        double sp = (s > 20.0) ? s : log1p(exp(s));
        double a  = (double)loc[0] + sp * (double)eps[0];
        a = fmin(fmax(a, 0.01), 0.99);
        double c = a * exp(-lgamma(1.0 - a)) * ((double)(NN - 1) / (double)KK);
        int j = lags[tid];
        j = (j < 1) ? 1 : ((j > NN - 1) ? NN - 1 : j);
        js_raw[tid] = j;
        ws_raw[tid] = (float)(c * exp(-(a + 1.0) * log((double)j)));
    }
    __syncthreads();
    if (tid < KK) {
        // parallel rank sort (64 compares/thread, ties broken by index)
        const int j = js_raw[tid];
        int rank = 0;
        for (int k = 0; k < KK; ++k) {
            const int jk = js_raw[k];
            rank += (int)((jk < j) || (jk == j && k < tid));
        }
        js[rank] = j;
        ws[rank] = ws_raw[tid];
    }
    __syncthreads();
    if (tid < 64) {               // first wave exactly: wave-wide ballots are valid
        const int j = js[tid];
#pragma unroll
        for (int i = 0; i < NCHUNK; ++i) {
            const int T = q * CHUNK + i * CHUNK_STRIDE;
            const unsigned long long mf = __ballot(j <= T);
            const unsigned long long mp = __ballot(j <= T + (CHUNK - 1));
            if (tid == 0) { cnt[i] = __popcll(mf); cnt[NCHUNK + i] = __popcll(mp); }
        }
    }
    __syncthreads();

    const float* __restrict__ xr = x + (size_t)b * NN;

    int    voff[NCHUNK];
    float  xt[NCHUNK];
    double acc[NCHUNK];
#pragma unroll
    for (int i = 0; i < NCHUNK; ++i) {
        voff[i] = q * CHUNK + i * CHUNK_STRIDE + tid;
        xt[i]   = xr[voff[i]];
        acc[i]  = 0.0;
    }

    const int cf0 = __builtin_amdgcn_readfirstlane(cnt[0]);
    const int cf1 = __builtin_amdgcn_readfirstlane(cnt[1]);
    const int cf2 = __builtin_amdgcn_readfirstlane(cnt[2]);
    const int cf3 = __builtin_amdgcn_readfirstlane(cnt[3]);

    // Branch-free segment loops over the sorted-lag prefix structure.
    int m = 0;
#pragma unroll 2
    for (; m < cf0; ++m) {        // lags fully valid for all 4 chunks
        const int    jj = __builtin_amdgcn_readfirstlane(js[m]);
        const double w  = (double)rfl_f(ws[m]);
        const float* bp = xr - jj;
#pragma unroll
        for (int i = 0; i < 4; ++i)
            acc[i] += (double)(xt[i] - bp[voff[i]]) * w;
    }
#pragma unroll 2
    for (; m < cf1; ++m) {        // chunks 1..3
        const int    jj = __builtin_amdgcn_readfirstlane(js[m]);
        const double w  = (double)rfl_f(ws[m]);
        const float* bp = xr - jj;
#pragma unroll
        for (int i = 1; i < 4; ++i)
            acc[i] += (double)(xt[i] - bp[voff[i]]) * w;
    }
#pragma unroll 2
    for (; m < cf2; ++m) {        // chunks 2..3
        const int    jj = __builtin_amdgcn_readfirstlane(js[m]);
        const double w  = (double)rfl_f(ws[m]);
        const float* bp = xr - jj;
#pragma unroll
        for (int i = 2; i < 4; ++i)
            acc[i] += (double)(xt[i] - bp[voff[i]]) * w;
    }
#pragma unroll 2
    for (; m < cf3; ++m) {        // chunk 3 only
        const int    jj = __builtin_amdgcn_readfirstlane(js[m]);
        const double w  = (double)rfl_f(ws[m]);
        const float* bp = xr - jj;
        acc[3] += (double)(xt[3] - bp[voff[3]]) * w;
    }

    // Straddle lags (j in (T[i], T[i]+255]): per-lane masked, ~0-1 iters/chunk.
#define STRADDLE(i, LO, HI)                                                     \
    for (int mm = (LO); mm < (HI); ++mm) {                                      \
        const int    jj = __builtin_amdgcn_readfirstlane(js[mm]);               \
        const double w  = (double)rfl_f(ws[mm]);                                \
        const int    d  = voff[i] - jj;                                         \
        const float  xg = xr[(d < 0) ? 0 : d];                                  \
        acc[i] += (d >= 0) ? (double)(xt[i] - xg) * w : 0.0;                    \
    }
    const int cp0 = __builtin_amdgcn_readfirstlane(cnt[4]);
    const int cp1 = __builtin_amdgcn_readfirstlane(cnt[5]);
    const int cp2 = __builtin_amdgcn_readfirstlane(cnt[6]);
    const int cp3 = __builtin_amdgcn_readfirstlane(cnt[7]);
    STRADDLE(0, cf0, cp0)
    STRADDLE(1, cf1, cp1)
    STRADDLE(2, cf2, cp2)
    STRADDLE(3, cf3, cp3)
#undef STRADDLE

    float* __restrict__ orow = out + (size_t)b * NN;
#pragma unroll
    for (int i = 0; i < NCHUNK; ++i) orow[voff[i]] = (float)acc[i];
}

extern "C" void kernel_launch(void* const* d_in, const int* in_sizes, int n_in,
                              void* d_out, int out_size, void* d_ws, size_t ws_size,
                              hipStream_t stream) {
    const float* x     = (const float*)d_in[0];
    const float* loc   = (const float*)d_in[1];
    const float* scale = (const float*)d_in[2];
    const float* eps   = (const float*)d_in[3];
    const int*   lags  = (const int*)d_in[4];
    float* out = (float*)d_out;

    const int nblocks = (BB * NN) / (TPB * NCHUNK); // 1024
    frac_deriv_kernel<<<nblocks, TPB, 0, stream>>>(x, loc, scale, eps, lags, out);
}

// Round 4
// 17.229 us; speedup vs baseline: 1.9029x; 1.2581x over previous
//
#include <hip/hip_runtime.h>

#define BB 16
#define NN 65536
#define KK 64
#define TPB 256
#define CHUNK 512                 // elements per block: two half-chunks of 256
#define NBLK ((BB * NN) / CHUNK)  // 2048 -> 8 blocks/CU -> 100% occupancy

__device__ __forceinline__ float readlane_f(float v, int lane) {
    return __uint_as_float((unsigned)__builtin_amdgcn_readlane((int)__float_as_uint(v), lane));
}

__global__ __launch_bounds__(TPB) void frac_deriv_kernel(
    const float* __restrict__ x,
    const float* __restrict__ loc,
    const float* __restrict__ scale,
    const float* __restrict__ eps,
    const int* __restrict__ lags,
    float* __restrict__ out)
{
    __shared__ int   js_raw[KK];
    __shared__ float ws_raw[KK];
    __shared__ int   js[KK];     // sorted ascending
    __shared__ float ws[KK];     // weights in sorted order
    __shared__ int   cnt[2];     // [0]=cf (j <= T, fully valid), [1]=cp (incl. straddle)

    const int tid = threadIdx.x;
    // Bijective XCD swizzle: 2048 blocks, each XCD gets 256 contiguous = 2 rows.
    const int bid = blockIdx.x;
    const int swz = (bid & 7) * (NBLK / 8) + (bid >> 3);
    const int b   = swz >> 7;        // row [0,16)   (128 blocks per row)
    const int q   = swz & 127;       // segment within row
    const int T   = q * CHUNK;

    if (tid < KK) {
        double s  = (double)scale[0];
        double sp = (s > 20.0) ? s : log1p(exp(s));
        double a  = (double)loc[0] + sp * (double)eps[0];
        a = fmin(fmax(a, 0.01), 0.99);
        double c = a * exp(-lgamma(1.0 - a)) * ((double)(NN - 1) / (double)KK);
        int j = lags[tid];
        j = (j < 1) ? 1 : ((j > NN - 1) ? NN - 1 : j);
        js_raw[tid] = j;
        ws_raw[tid] = (float)(c * exp(-(a + 1.0) * log((double)j)));
    }
    __syncthreads();
    if (tid < KK) {
        // parallel rank sort (ties broken by index)
        const int j = js_raw[tid];
        int rank = 0;
        for (int k = 0; k < KK; ++k) {
            const int jk = js_raw[k];
            rank += (int)((jk < j) || (jk == j && k < tid));
        }
        js[rank] = j;
        ws[rank] = ws_raw[tid];
    }
    __syncthreads();
    if (tid < 64) {                  // exactly wave 0: wave-wide ballot valid
        const int j = js[tid];
        const unsigned long long mf = __ballot(j <= T);
        const unsigned long long mp = __ballot(j <= T + (CHUNK - 1));
        if (tid == 0) { cnt[0] = __popcll(mf); cnt[1] = __popcll(mp); }
    }
    __syncthreads();

    // Lane-resident copies: lane m holds sorted j_m / w_m -> hot loop uses
    // v_readlane (no LDS latency chain per iteration).
    const int   jv = js[tid & 63];
    const float wv = ws[tid & 63];

    const float* __restrict__ xr = x + (size_t)b * NN;
    const float xt0 = xr[T + tid];
    const float xt1 = xr[T + 256 + tid];

    double acc0 = 0.0, acc1 = 0.0;

    const int cf  = __builtin_amdgcn_readfirstlane(cnt[0]);
    const int cp  = __builtin_amdgcn_readfirstlane(cnt[1]);
    const int cf8 = cf & ~7;

    // Fully-valid lags, groups of 8, f32 partials flushed to f64.
    for (int mo = 0; mo < cf8; mo += 8) {
        float g0 = 0.0f, g1 = 0.0f;
#pragma unroll
        for (int mi = 0; mi < 8; ++mi) {
            const int   m  = mo + mi;
            const int   jj = __builtin_amdgcn_readlane(jv, m);
            const float w  = readlane_f(wv, m);
            const float* bp = xr + (T - jj);   // scalar base; vaddr = tid*4 shared
            const float x0 = bp[tid];          // offset:0
            const float x1 = bp[tid + 256];    // offset:1024 (immediate)
            g0 = fmaf(xt0 - x0, w, g0);
            g1 = fmaf(xt1 - x1, w, g1);
        }
        acc0 += (double)g0;
        acc1 += (double)g1;
    }
    // Remainder of fully-valid lags.
    for (int m = cf8; m < cf; ++m) {
        const int   jj = __builtin_amdgcn_readlane(jv, m);
        const float w  = readlane_f(wv, m);
        const float* bp = xr + (T - jj);
        acc0 += (double)((xt0 - bp[tid]) * w);
        acc1 += (double)((xt1 - bp[tid + 256]) * w);
    }
    // Straddle lags (T < j <= T+511): per-lane masked clamp, ~0-1 iters typical.
    for (int m = cf; m < cp; ++m) {
        const int   jj = __builtin_amdgcn_readlane(jv, m);
        const float w  = readlane_f(wv, m);
        const int d0 = T + tid - jj;
        const int d1 = d0 + 256;
        const float g0v = xr[(d0 < 0) ? 0 : d0];
        const float g1v = xr[(d1 < 0) ? 0 : d1];
        acc0 += (d0 >= 0) ? (double)((xt0 - g0v) * w) : 0.0;
        acc1 += (d1 >= 0) ? (double)((xt1 - g1v) * w) : 0.0;
    }

    float* __restrict__ orow = out + (size_t)b * NN;
    orow[T + tid]       = (float)acc0;
    orow[T + 256 + tid] = (float)acc1;
}

extern "C" void kernel_launch(void* const* d_in, const int* in_sizes, int n_in,
                              void* d_out, int out_size, void* d_ws, size_t ws_size,
                              hipStream_t stream) {
    const float* x     = (const float*)d_in[0];
    const float* loc   = (const float*)d_in[1];
    const float* scale = (const float*)d_in[2];
    const float* eps   = (const float*)d_in[3];
    const int*   lags  = (const int*)d_in[4];
    float* out = (float*)d_out;

    frac_deriv_kernel<<<NBLK, TPB, 0, stream>>>(x, loc, scale, eps, lags, out);
}